// Round 8
// baseline (54.562 us; speedup 1.0000x reference)
//
#include <hip/hip_runtime.h>
#include <math.h>

#define T_TOK 8192
#define DDIM  4096
#define NEXP  64
#define TOPK  8
#define WAVES 8
#define STEPS 16          // 512 k per wave (DDIM / WAVES / 32)

typedef __attribute__((ext_vector_type(8))) _Float16 half8;
typedef __attribute__((ext_vector_type(4))) float f32x4;

#define RS 2048.0f

// ---- K0: pack gate_weight [E][D] f32 into MFMA B-fragment order, split f16.
// wpk[(kt*4 + n)*2 + p][lane][8], p=0: h0, p=1: (w-h0)*2048.
// B frag (16x16x32): expert col = n*16 + (lane&15), k = kt*32 + (lane>>4)*8 + j.
__global__ __launch_bounds__(256) void pack_w(
    const float* __restrict__ gw, _Float16* __restrict__ wpk)
{
    const int g    = blockIdx.x * 256 + threadIdx.x;
    const int lane = g & 63;
    const int n    = (g >> 6) & 3;
    const int kt   = g >> 8;                     // 0..127
    const int e    = n * 16 + (lane & 15);
    const int k    = kt * 32 + (lane >> 4) * 8;

    const float* src = gw + (size_t)e * DDIM + k;
    float4 v0 = *reinterpret_cast<const float4*>(src);
    float4 v1 = *reinterpret_cast<const float4*>(src + 4);
    const float v[8] = {v0.x, v0.y, v0.z, v0.w, v1.x, v1.y, v1.z, v1.w};

    half8 h0, h1;
    #pragma unroll
    for (int j = 0; j < 8; j++) {
        _Float16 a = (_Float16)v[j];
        h0[j] = a;
        h1[j] = (_Float16)((v[j] - (float)a) * RS);
    }
    size_t base = ((size_t)(kt * 4 + n) * 2) * 512;
    *reinterpret_cast<half8*>(wpk + base + lane * 8)       = h0;
    *reinterpret_cast<half8*>(wpk + base + 512 + lane * 8) = h1;
}

// ---- K1: fully fused logits GEMM + reduce + sigmoid + top-8 ----
// 512 thr = 8 waves.  Block = 32 tokens.  Wave wv: 32 tok x 64 exp x k-slice
// [wv*512, wv*512+512).  Barrier-free main loop (R7 pipeline: A 2 ahead
// depth-3, B 1 ahead depth-2, B stream shared by both 16-row M-frags).
// Epilogue: LDS 8-slice reduce, then per-wave top-8 on 4 tokens.
__global__ __launch_bounds__(512, 2) void gemm_topk(
    const float* __restrict__ x, const _Float16* __restrict__ wpk,
    const float* __restrict__ bias, float* __restrict__ out)
{
    __shared__ float red[WAVES][32][NEXP];       // 64 KB

    const int tid  = threadIdx.x;
    const int lane = tid & 63;
    const int wv   = tid >> 6;                   // k-slice
    const int tok0 = blockIdx.x * 32;
    const int am   = lane & 15;
    const int ag   = lane >> 4;

    const float* xr0 = x + (size_t)(tok0 + am) * DDIM + wv * (DDIM / WAVES) + ag * 8;
    const float* xr1 = xr0 + (size_t)16 * DDIM;
    const _Float16* bbase = wpk + (size_t)(wv * STEPS) * 8 * 512 + lane * 8;

    f32x4 aH[2][4], aM[2][4];
    #pragma unroll
    for (int t = 0; t < 2; t++)
        #pragma unroll
        for (int n = 0; n < 4; n++) {
            aH[t][n] = (f32x4){0.f, 0.f, 0.f, 0.f};
            aM[t][n] = (f32x4){0.f, 0.f, 0.f, 0.f};
        }

    float4 av[3][4];     // A pipeline, depth 3 (2-step lookahead)
    half8  bf[2][8];     // B pipeline, depth 2

    #pragma unroll
    for (int st = 0; st < 2; st++) {
        av[st][0] = *reinterpret_cast<const float4*>(xr0 + st * 32);
        av[st][1] = *reinterpret_cast<const float4*>(xr0 + st * 32 + 4);
        av[st][2] = *reinterpret_cast<const float4*>(xr1 + st * 32);
        av[st][3] = *reinterpret_cast<const float4*>(xr1 + st * 32 + 4);
    }
    #pragma unroll
    for (int n = 0; n < 4; n++) {
        bf[0][2 * n]     = *reinterpret_cast<const half8*>(bbase + n * 1024);
        bf[0][2 * n + 1] = *reinterpret_cast<const half8*>(bbase + n * 1024 + 512);
    }

    #pragma unroll
    for (int st = 0; st < STEPS; st++) {
        const int cur  = st & 1;
        const int nxt  = cur ^ 1;
        const int acur = st % 3;

        if (st + 2 < STEPS) {                     // A prefetch, 2 ahead
            const int ap = (st + 2) % 3;
            av[ap][0] = *reinterpret_cast<const float4*>(xr0 + (st + 2) * 32);
            av[ap][1] = *reinterpret_cast<const float4*>(xr0 + (st + 2) * 32 + 4);
            av[ap][2] = *reinterpret_cast<const float4*>(xr1 + (st + 2) * 32);
            av[ap][3] = *reinterpret_cast<const float4*>(xr1 + (st + 2) * 32 + 4);
        }
        if (st + 1 < STEPS) {                     // B prefetch, 1 ahead
            const _Float16* bp = bbase + (size_t)(st + 1) * 8 * 512;
            #pragma unroll
            for (int n = 0; n < 4; n++) {
                bf[nxt][2 * n]     = *reinterpret_cast<const half8*>(bp + n * 1024);
                bf[nxt][2 * n + 1] = *reinterpret_cast<const half8*>(bp + n * 1024 + 512);
            }
        }

        half8 a0[2], a1[2];
        #pragma unroll
        for (int t = 0; t < 2; t++) {
            const float* vv = reinterpret_cast<const float*>(&av[acur][2 * t]);
            #pragma unroll
            for (int j = 0; j < 8; j++) {
                float v = vv[j];
                _Float16 h = (_Float16)v;
                a0[t][j] = h;
                a1[t][j] = (_Float16)((v - (float)h) * RS);
            }
        }
        #pragma unroll
        for (int t = 0; t < 2; t++)
            #pragma unroll
            for (int n = 0; n < 4; n++) {
                aH[t][n] = __builtin_amdgcn_mfma_f32_16x16x32_f16(a0[t], bf[cur][2 * n],     aH[t][n], 0, 0, 0);
                aM[t][n] = __builtin_amdgcn_mfma_f32_16x16x32_f16(a0[t], bf[cur][2 * n + 1], aM[t][n], 0, 0, 0);
                aM[t][n] = __builtin_amdgcn_mfma_f32_16x16x32_f16(a1[t], bf[cur][2 * n],     aM[t][n], 0, 0, 0);
            }
    }

    // ---- dump plane-combined slice logits to LDS ----
    // C/D layout (m89): col = lane&15 (expert), row = (lane>>4)*4 + r (token)
    const float i1 = 1.0f / RS;
    #pragma unroll
    for (int t = 0; t < 2; t++)
        #pragma unroll
        for (int n = 0; n < 4; n++)
            #pragma unroll
            for (int r = 0; r < 4; r++)
                red[wv][t * 16 + ag * 4 + r][n * 16 + am]
                    = aH[t][n][r] + aM[t][n][r] * i1;
    __syncthreads();

    // ---- 8-slice reduce in place: thread (tok, c4) owns 4 experts ----
    {
        const int tok = tid >> 4;                // 0..31
        const int c4  = tid & 15;
        float4 s0 = *reinterpret_cast<const float4*>(&red[0][tok][c4 * 4]);
        #pragma unroll
        for (int s = 1; s < WAVES; s++) {
            float4 v = *reinterpret_cast<const float4*>(&red[s][tok][c4 * 4]);
            s0.x += v.x; s0.y += v.y; s0.z += v.z; s0.w += v.w;
        }
        *reinterpret_cast<float4*>(&red[0][tok][c4 * 4]) = s0;   // each (tok,c4) has one owner
    }
    __syncthreads();

    // ---- top-8: wave wv handles tokens wv*4 .. wv*4+3, lane = expert ----
    const float bsv = bias[lane];
    #pragma unroll
    for (int ti = 0; ti < 4; ti++) {
        const int tk = wv * 4 + ti;
        float logit  = red[0][tk][lane];
        float score  = 1.f / (1.f + expf(-logit));
        float biased = score + bsv;
        float my_sc = 0.f; int my_idx = 0; float ssum = 0.f;
        #pragma unroll
        for (int j = 0; j < TOPK; j++) {
            float vb = biased; int ib = lane;
            #pragma unroll
            for (int off = 32; off >= 1; off >>= 1) {
                float ov = __shfl_xor(vb, off);
                int   oi = __shfl_xor(ib, off);
                if (ov > vb || (ov == vb && oi < ib)) { vb = ov; ib = oi; }
            }
            float s_sel = __shfl(score, ib);
            ssum += s_sel;
            if (lane == j) { my_idx = ib; my_sc = s_sel; }
            if (lane == ib) biased = -INFINITY;
        }
        if (lane < TOPK) {
            out[(size_t)(tok0 + tk) * TOPK + lane] = (float)my_idx;           // indices as f32
            out[(size_t)T_TOK * TOPK + (size_t)(tok0 + tk) * TOPK + lane]
                = my_sc / (ssum + 1e-20f);                                    // weights
        }
    }
}

extern "C" void kernel_launch(void* const* d_in, const int* in_sizes, int n_in,
                              void* d_out, int out_size, void* d_ws, size_t ws_size,
                              hipStream_t stream) {
    (void)in_sizes; (void)n_in; (void)out_size; (void)ws_size;
    const float* x    = (const float*)d_in[0];
    const float* gw   = (const float*)d_in[1];
    const float* bias = (const float*)d_in[2];
    float* out = (float*)d_out;
    _Float16* wpk = (_Float16*)d_ws;             // 1 MiB packed W frags

    pack_w<<<128, 256, 0, stream>>>(gw, wpk);
    gemm_topk<<<T_TOK / 32, 512, 0, stream>>>(x, wpk, bias, out);
}